// Round 4
// baseline (714.479 us; speedup 1.0000x reference)
//
#include <hip/hip_runtime.h>

// Problem constants (B=64, N=600, C=256)
#define B_DIM 64
#define N_NODES 600
#define C_DIM 256
#define NV4 (N_NODES / 4)          // 150 float4 per A row
#define XROWS (B_DIM * N_NODES)    // 38400
#define XBLOCKS (XROWS / 4)        // 9600 (4 rows per 256-thr block)
#define BLK_PER_B (N_NODES / 4)    // 150 score blocks per batch
#define A_ROWTILE 16
#define ABLK_PER_B ((N_NODES + A_ROWTILE - 1) / A_ROWTILE)  // 38
#define ABLOCKS (B_DIM * ABLK_PER_B)                        // 2432

constexpr float kThr = 0.003f;   // THRESHOLD
constexpr float kEps = 1e-7f;    // EPS

// ---------------------------------------------------------------------------
// K1: scores (wide, 9600 blocks) + per-batch last-block compaction fused.
// Score phase: one wave per (b,n) row, float4 dot, exp*mask -> alpha_pre.
// The last block of each batch (per-batch atomic counter) then normalizes,
// thresholds, and computes the stable compaction index for that batch.
// Sum emulates the 1024-wide tree EXACTLY with 256 threads:
//   b_t = (ap[t] + ap[t+512]) + ap[t+256], then identical 128..1 LDS tree.
// ---------------------------------------------------------------------------
__global__ __launch_bounds__(256)
void k_scores_compact(const float* __restrict__ x,
                      const float* __restrict__ W,
                      const int* __restrict__ mask,
                      float* __restrict__ alpha,     // ws: (B,N) pre->norm
                      int* __restrict__ idx,         // ws: (B,N)
                      int* __restrict__ Kbuf,        // ws: (B)
                      float* __restrict__ mask_out,  // out: (B,N)
                      unsigned int* __restrict__ counters) {  // ws: (B), zeroed
  const int bid  = blockIdx.x;
  const int b    = bid / BLK_PER_B;
  const int wave = threadIdx.x >> 6;
  const int lane = threadIdx.x & 63;
  const int row  = bid * 4 + wave;         // b*N + n

  // ---- score phase ----
  {
    const float4 xv = reinterpret_cast<const float4*>(x + (size_t)row * C_DIM)[lane];
    const float4 wv = reinterpret_cast<const float4*>(W)[lane];
    float s = xv.x * wv.x + xv.y * wv.y + xv.z * wv.z + xv.w * wv.w;
    #pragma unroll
    for (int off = 32; off > 0; off >>= 1) s += __shfl_down(s, off, 64);
    if (lane == 0) {
      const float ap = (mask[row] != 0) ? expf(s) : 0.0f;
      // agent-scope store so the compaction block (possibly another XCD) sees it
      __hip_atomic_store(&alpha[row], ap, __ATOMIC_RELAXED,
                         __HIP_MEMORY_SCOPE_AGENT);
    }
  }
  __threadfence();
  __syncthreads();

  __shared__ int slast;
  if (threadIdx.x == 0) {
    const unsigned int done = atomicAdd(&counters[b], 1u);
    slast = (done == BLK_PER_B - 1) ? 1 : 0;
  }
  __syncthreads();
  if (!slast) return;
  __threadfence();

  // ---- compaction phase: this block owns batch b ----
  const int t = threadIdx.x;
  __shared__ float sAP[N_NODES];
  __shared__ float fs[256];
  __shared__ int   wtot[4];

  float* ab = alpha + b * N_NODES;
  for (int n = t; n < N_NODES; n += 256)
    sAP[n] = __hip_atomic_load(&ab[n], __ATOMIC_RELAXED,
                               __HIP_MEMORY_SCOPE_AGENT);
  __syncthreads();

  // exact 1024-tree emulation (t < 256):
  float v = sAP[t];
  if (t < N_NODES - 512) v += sAP[t + 512];   // level 512 (ap[t]+ap[t+512])
  v += sAP[t + 256];                          // level 256 (+ap[t+256]); t+256<512<600
  fs[t] = v;
  __syncthreads();
  #pragma unroll
  for (int off = 128; off > 0; off >>= 1) {
    if (t < off) fs[t] += fs[t + off];
    __syncthreads();
  }
  const float S = fs[0];

  // contiguous 3-nodes-per-thread (threads 0..199): alpha, keep, local count
  float a3[3];
  int   k3[3];
  int   c = 0;
  const int n0 = t * 3;
  if (t < 200) {
    #pragma unroll
    for (int k = 0; k < 3; ++k) {
      const float a = sAP[n0 + k] / (S + kEps);
      a3[k] = a;
      k3[k] = (a > kThr) ? 1 : 0;   // mask==0 => ap==0 => a==0 => not kept
      c += k3[k];
    }
  }

  // exclusive scan of c over 256 threads (wave scan + wave-total combine)
  int incl = c;
  #pragma unroll
  for (int off = 1; off < 64; off <<= 1) {
    const int u = __shfl_up(incl, off, 64);
    if (lane >= off) incl += u;
  }
  if (lane == 63) wtot[wave] = incl;
  __syncthreads();
  int offtot = 0, Ktot = 0;
  #pragma unroll
  for (int w2 = 0; w2 < 4; ++w2) {
    const int u = wtot[w2];
    if (w2 < wave) offtot += u;
    Ktot += u;
  }
  const int K = Ktot;
  int run = incl - c + offtot;   // kept nodes before n0

  if (t == 0) Kbuf[b] = K;
  if (t < 200) {
    #pragma unroll
    for (int k = 0; k < 3; ++k) {
      const int n = n0 + k;
      ab[n] = a3[k];                       // normalized alpha
      if (k3[k]) { idx[b * N_NODES + run] = n; ++run; }
      else       { idx[b * N_NODES + K + (n - run)] = n; }
    }
  }
  for (int n = t; n < N_NODES; n += 256)
    mask_out[b * N_NODES + n] = (n < K) ? 1.0f : 0.0f;
}

// ---------------------------------------------------------------------------
// K2: fused gathers. Blocks [0, XBLOCKS): x-gather (wave per row, float4).
// Blocks [XBLOCKS, XBLOCKS+ABLOCKS): A-gather, 16 rows per block,
// wave per row, float4 writes; j-loop split at the K/4 boundary.
// ---------------------------------------------------------------------------
__global__ __launch_bounds__(256)
void k_gather(const float* __restrict__ x,
              const float* __restrict__ A,
              const float* __restrict__ alpha,
              const int* __restrict__ idx,
              const int* __restrict__ Kbuf,
              float* __restrict__ xo,
              float* __restrict__ Ao) {
  const int bid  = blockIdx.x;
  const int t    = threadIdx.x;
  const int wave = t >> 6;
  const int lane = t & 63;

  if (bid < XBLOCKS) {
    // ---- x part: xo[b,i,:] = x[b, idx[b,i], :] * alpha[b, idx[b,i]] ----
    const int row = bid * 4 + wave;          // b*N + i
    const int b   = row / N_NODES;
    const int src = idx[row];
    const float a = alpha[b * N_NODES + src];
    float4 v = reinterpret_cast<const float4*>(
        x + ((size_t)b * N_NODES + src) * C_DIM)[lane];
    v.x *= a; v.y *= a; v.z *= a; v.w *= a;
    reinterpret_cast<float4*>(xo + (size_t)row * C_DIM)[lane] = v;
  } else {
    // ---- A part ----
    const int abid = bid - XBLOCKS;
    const int b    = abid / ABLK_PER_B;
    const int i0   = (abid % ABLK_PER_B) * A_ROWTILE;

    __shared__ int sidx[N_NODES];
    const int K = Kbuf[b];
    for (int j = t; j < K; j += 256) sidx[j] = idx[b * N_NODES + j];
    __syncthreads();

    const int kq = K >> 2;                   // float4s fully inside [0,K)
    const float* Ab  = A  + (size_t)b * N_NODES * N_NODES;
    float*       Aob = Ao + (size_t)b * N_NODES * N_NODES;

    for (int ii = wave; ii < A_ROWTILE; ii += 4) {
      const int i = i0 + ii;
      if (i >= N_NODES) break;
      float4* orow = reinterpret_cast<float4*>(Aob + (size_t)i * N_NODES);
      if (i < K) {
        const float* Arow = Ab + (size_t)sidx[i] * N_NODES;
        for (int j4 = lane; j4 < NV4; j4 += 64) {
          float4 v = {0.0f, 0.0f, 0.0f, 0.0f};
          if (j4 < kq) {
            const int j = j4 * 4;
            v.x = Arow[sidx[j + 0]];
            v.y = Arow[sidx[j + 1]];
            v.z = Arow[sidx[j + 2]];
            v.w = Arow[sidx[j + 3]];
          } else if (j4 == kq) {
            const int j = j4 * 4;
            if (j + 0 < K) v.x = Arow[sidx[j + 0]];
            if (j + 1 < K) v.y = Arow[sidx[j + 1]];
            if (j + 2 < K) v.z = Arow[sidx[j + 2]];
          }
          orow[j4] = v;
        }
      } else {
        const float4 z = {0.0f, 0.0f, 0.0f, 0.0f};
        for (int j4 = lane; j4 < NV4; j4 += 64) orow[j4] = z;
      }
    }
  }
}

// ---------------------------------------------------------------------------
extern "C" void kernel_launch(void* const* d_in, const int* in_sizes, int n_in,
                              void* d_out, int out_size, void* d_ws, size_t ws_size,
                              hipStream_t stream) {
  const float* x    = (const float*)d_in[0];
  const float* A    = (const float*)d_in[1];
  const int*   mask = (const int*)d_in[2];
  const float* W    = (const float*)d_in[3];

  const size_t BN = (size_t)B_DIM * N_NODES;

  float* xo = (float*)d_out;                       // (B,N,C)
  float* Ao = xo + BN * C_DIM;                     // (B,N,N)
  float* mo = Ao + BN * N_NODES;                   // (B,N) as 0.0/1.0

  // workspace layout
  float*        alpha    = (float*)d_ws;           // B*N floats
  int*          idx      = (int*)(alpha + BN);     // B*N ints
  int*          Kbuf     = idx + BN;               // B ints
  unsigned int* counters = (unsigned int*)(Kbuf + B_DIM);  // B uints

  hipMemsetAsync(counters, 0, B_DIM * sizeof(unsigned int), stream);
  k_scores_compact<<<XBLOCKS, 256, 0, stream>>>(x, W, mask, alpha, idx, Kbuf,
                                                mo, counters);
  k_gather<<<XBLOCKS + ABLOCKS, 256, 0, stream>>>(x, A, alpha, idx, Kbuf, xo, Ao);
}

// Round 5
// 44.689 us; speedup vs baseline: 15.9876x; 15.9876x over previous
//
#include <hip/hip_runtime.h>

// Problem constants (B=64, N=600, C=256)
#define B_DIM 64
#define N_NODES 600
#define C_DIM 256
#define NV4 (N_NODES / 4)          // 150 float4 per A row
#define XROWS (B_DIM * N_NODES)    // 38400
#define XBLOCKS (XROWS / 4)        // 9600 (4 rows per 256-thr block)

// Ao zero-fill: 64*600*600 floats = 5,760,000 float4
#define AO_F4 (B_DIM * N_NODES * NV4)
#define ZBLOCKS 1440
#define ZCHUNK (AO_F4 / ZBLOCKS)   // 4000 float4 per block (exact)

#define A_ROWTILE 16
#define ABLK_PER_B ((N_NODES + A_ROWTILE - 1) / A_ROWTILE)  // 38
#define ABLOCKS (B_DIM * ABLK_PER_B)                        // 2432

constexpr float kThr = 0.003f;   // THRESHOLD
constexpr float kEps = 1e-7f;    // EPS

// ---------------------------------------------------------------------------
// K_a: blocks [0, XBLOCKS): scores per row (wave per row, float4 dot).
//      blocks [XBLOCKS, XBLOCKS+ZBLOCKS): zero-fill ALL of Ao.
// The zero-fill has no dependency on scores, so it overlaps the x-read here
// instead of serializing inside the final gather kernel.
// NO device-scope fences/atomics anywhere (R4 lesson: 16x regression).
// ---------------------------------------------------------------------------
__global__ __launch_bounds__(256)
void k_scores_zero(const float* __restrict__ x,
                   const float* __restrict__ W,
                   const int* __restrict__ mask,
                   float* __restrict__ alpha_pre,
                   float4* __restrict__ Ao4) {
  const int bid = blockIdx.x;
  if (bid < XBLOCKS) {
    const int row  = bid * 4 + (threadIdx.x >> 6);  // b*N + n
    const int lane = threadIdx.x & 63;
    const float4 xv = reinterpret_cast<const float4*>(x + (size_t)row * C_DIM)[lane];
    const float4 wv = reinterpret_cast<const float4*>(W)[lane];
    float s = xv.x * wv.x + xv.y * wv.y + xv.z * wv.z + xv.w * wv.w;
    #pragma unroll
    for (int off = 32; off > 0; off >>= 1) s += __shfl_down(s, off, 64);
    if (lane == 0) {
      alpha_pre[row] = (mask[row] != 0) ? expf(s) : 0.0f;
    }
  } else {
    const int zb = bid - XBLOCKS;
    float4* dst = Ao4 + (size_t)zb * ZCHUNK;
    const float4 z = {0.0f, 0.0f, 0.0f, 0.0f};
    for (int i = threadIdx.x; i < ZCHUNK; i += 256) dst[i] = z;
  }
}

// ---------------------------------------------------------------------------
// K_b: per-batch normalize + threshold + stable compaction (R3 verbatim —
// known-good numerics). One block (1024 thr) per batch.
// ---------------------------------------------------------------------------
__global__ __launch_bounds__(1024)
void k_compact(float* __restrict__ alpha,     // in: alpha_pre, out: alpha
               int* __restrict__ idx,
               int* __restrict__ Kbuf,
               float* __restrict__ mask_out) {
  const int b    = blockIdx.x;
  const int t    = threadIdx.x;
  const int wave = t >> 6;
  const int lane = t & 63;

  __shared__ float fs[1024];
  __shared__ int   wtot[16];

  const float ap = (t < N_NODES) ? alpha[b * N_NODES + t] : 0.0f;

  // balanced tree sum (identical order to round-0 passing kernel)
  fs[t] = ap;
  __syncthreads();
  #pragma unroll
  for (int off = 512; off > 0; off >>= 1) {
    if (t < off) fs[t] += fs[t + off];
    __syncthreads();
  }
  const float S = fs[0];

  const float a = ap / (S + kEps);
  // mask==0 => ap==0 => a==0 => not kept, so (a > thr) alone suffices
  const int keep = (t < N_NODES && a > kThr) ? 1 : 0;

  // wave-level inclusive scan of keep
  int incl = keep;
  #pragma unroll
  for (int off = 1; off < 64; off <<= 1) {
    int v = __shfl_up(incl, off, 64);
    if (lane >= off) incl += v;
  }
  if (lane == 63) wtot[wave] = incl;
  __syncthreads();
  int offtot = 0, Ktot = 0;
  #pragma unroll
  for (int w2 = 0; w2 < 16; ++w2) {
    const int v = wtot[w2];
    if (w2 < wave) offtot += v;
    Ktot += v;
  }
  incl += offtot;
  const int K = Ktot;

  if (t < N_NODES) {
    const int pos = keep ? (incl - 1) : (K + (t - incl));
    idx[b * N_NODES + pos]    = t;
    alpha[b * N_NODES + t]    = a;
    mask_out[b * N_NODES + t] = (t < K) ? 1.0f : 0.0f;
    if (t == 0) Kbuf[b] = K;
  }
}

// ---------------------------------------------------------------------------
// K_c: blocks [0, XBLOCKS): x-gather (wave per row, float4).
//      blocks [XBLOCKS, ...): A-gather — ONLY rows i<K, cols [0, K);
//      everything else is already zero from K_a. Blocks whose row tile is
//      entirely >= K exit immediately.
// ---------------------------------------------------------------------------
__global__ __launch_bounds__(256)
void k_gather(const float* __restrict__ x,
              const float* __restrict__ A,
              const float* __restrict__ alpha,
              const int* __restrict__ idx,
              const int* __restrict__ Kbuf,
              float* __restrict__ xo,
              float* __restrict__ Ao) {
  const int bid  = blockIdx.x;
  const int t    = threadIdx.x;
  const int wave = t >> 6;
  const int lane = t & 63;

  if (bid < XBLOCKS) {
    // ---- x part: xo[b,i,:] = x[b, idx[b,i], :] * alpha[b, idx[b,i]] ----
    const int row = bid * 4 + wave;          // b*N + i
    const int b   = row / N_NODES;
    const int src = idx[row];
    const float a = alpha[b * N_NODES + src];
    float4 v = reinterpret_cast<const float4*>(
        x + ((size_t)b * N_NODES + src) * C_DIM)[lane];
    v.x *= a; v.y *= a; v.z *= a; v.w *= a;
    reinterpret_cast<float4*>(xo + (size_t)row * C_DIM)[lane] = v;
  } else {
    // ---- A part: write only the K x K gathered block ----
    const int abid = bid - XBLOCKS;
    const int b    = abid / ABLK_PER_B;
    const int i0   = (abid % ABLK_PER_B) * A_ROWTILE;

    const int K = Kbuf[b];
    if (i0 >= K) return;                     // tile fully below threshold rows

    __shared__ int sidx[N_NODES];
    for (int j = t; j < K; j += 256) sidx[j] = idx[b * N_NODES + j];
    __syncthreads();

    const int kq = K >> 2;                   // float4s fully inside [0,K)
    const float* Ab  = A  + (size_t)b * N_NODES * N_NODES;
    float*       Aob = Ao + (size_t)b * N_NODES * N_NODES;

    for (int ii = wave; ii < A_ROWTILE; ii += 4) {
      const int i = i0 + ii;
      if (i >= K) break;
      float4* orow = reinterpret_cast<float4*>(Aob + (size_t)i * N_NODES);
      const float* Arow = Ab + (size_t)sidx[i] * N_NODES;
      // write only j4 in [0, kq]; tail beyond K stays zero from K_a
      for (int j4 = lane; j4 <= kq && j4 < NV4; j4 += 64) {
        float4 v = {0.0f, 0.0f, 0.0f, 0.0f};
        if (j4 < kq) {
          const int j = j4 * 4;
          v.x = Arow[sidx[j + 0]];
          v.y = Arow[sidx[j + 1]];
          v.z = Arow[sidx[j + 2]];
          v.w = Arow[sidx[j + 3]];
        } else {
          const int j = j4 * 4;
          if (j + 0 < K) v.x = Arow[sidx[j + 0]];
          if (j + 1 < K) v.y = Arow[sidx[j + 1]];
          if (j + 2 < K) v.z = Arow[sidx[j + 2]];
        }
        orow[j4] = v;
      }
    }
  }
}

// ---------------------------------------------------------------------------
extern "C" void kernel_launch(void* const* d_in, const int* in_sizes, int n_in,
                              void* d_out, int out_size, void* d_ws, size_t ws_size,
                              hipStream_t stream) {
  const float* x    = (const float*)d_in[0];
  const float* A    = (const float*)d_in[1];
  const int*   mask = (const int*)d_in[2];
  const float* W    = (const float*)d_in[3];

  const size_t BN = (size_t)B_DIM * N_NODES;

  float* xo = (float*)d_out;                       // (B,N,C)
  float* Ao = xo + BN * C_DIM;                     // (B,N,N)
  float* mo = Ao + BN * N_NODES;                   // (B,N) as 0.0/1.0

  // workspace layout
  float* alpha = (float*)d_ws;                     // B*N floats
  int*   idx   = (int*)(alpha + BN);               // B*N ints
  int*   Kbuf  = idx + BN;                         // B ints

  k_scores_zero<<<XBLOCKS + ZBLOCKS, 256, 0, stream>>>(
      x, W, mask, alpha, (float4*)Ao);
  k_compact<<<B_DIM, 1024, 0, stream>>>(alpha, idx, Kbuf, mo);
  k_gather<<<XBLOCKS + ABLOCKS, 256, 0, stream>>>(x, A, alpha, idx, Kbuf, xo, Ao);
}

// Round 6
// 42.054 us; speedup vs baseline: 16.9895x; 1.0627x over previous
//
#include <hip/hip_runtime.h>

// Problem constants (B=64, N=600, C=256)
#define B_DIM 64
#define N_NODES 600
#define C_DIM 256
#define NV4 (N_NODES / 4)              // 150 float4 per A row
#define ROWTILE 16
#define BLK_PER_B ((N_NODES + ROWTILE - 1) / ROWTILE)   // 38
#define GBLOCKS (B_DIM * BLK_PER_B)    // 2432
#define SBLOCKS (B_DIM * N_NODES / 4)  // 9600

constexpr float kThr = 0.003f;   // THRESHOLD
constexpr float kEps = 1e-7f;    // EPS

// ---------------------------------------------------------------------------
// K1: scores = x . W per (b,n) row -> alpha_pre = exp(score)*mask.
// Wide: 9600 blocks, one wave per row, float4 dot. (R2 lesson: big reads
// need full-chip parallelism.)
// ---------------------------------------------------------------------------
__global__ __launch_bounds__(256)
void k_scores(const float* __restrict__ x,
              const float* __restrict__ W,
              const int* __restrict__ mask,
              float* __restrict__ alpha_pre) {
  const int row  = blockIdx.x * 4 + (threadIdx.x >> 6);  // b*N + n
  const int lane = threadIdx.x & 63;
  const float4 xv = reinterpret_cast<const float4*>(x + (size_t)row * C_DIM)[lane];
  const float4 wv = reinterpret_cast<const float4*>(W)[lane];
  float s = xv.x * wv.x + xv.y * wv.y + xv.z * wv.z + xv.w * wv.w;
  #pragma unroll
  for (int off = 32; off > 0; off >>= 1) s += __shfl_down(s, off, 64);
  if (lane == 0) alpha_pre[row] = (mask[row] != 0) ? expf(s) : 0.0f;
}

// ---------------------------------------------------------------------------
// K2: one block per (batch, 16-row output tile). Each block REDUNDANTLY
// recomputes the batch compaction from alpha_pre (pure function -> identical
// result in every block; no cross-block comm, no fences — R4 lesson).
// Sum = bit-exact 256-thread emulation of the 1024-wide tree (validated R4).
// Then: x-row gather (float4) + full A-row write (gather cols < K, zeros
// elsewhere). Block with i0==0 also writes mask_out.
// ---------------------------------------------------------------------------
__global__ __launch_bounds__(256)
void k_gather(const float* __restrict__ x,
              const float* __restrict__ A,
              const float* __restrict__ alpha_pre,
              float* __restrict__ xo,
              float* __restrict__ Ao,
              float* __restrict__ mo) {
  const int bid  = blockIdx.x;
  const int b    = bid / BLK_PER_B;
  const int i0   = (bid % BLK_PER_B) * ROWTILE;
  const int t    = threadIdx.x;
  const int wave = t >> 6;
  const int lane = t & 63;

  __shared__ float sAP[N_NODES];
  __shared__ float fs[256];
  __shared__ int   wtot[4];
  __shared__ int   sidx[N_NODES];

  // ---- local compact ----
  const float* ab = alpha_pre + b * N_NODES;
  for (int n = t; n < N_NODES; n += 256) sAP[n] = ab[n];
  __syncthreads();

  // exact 1024-tree emulation with 256 threads:
  float v = sAP[t];
  if (t < N_NODES - 512) v += sAP[t + 512];   // level 512
  v += sAP[t + 256];                          // level 256 (t+256 < 512 < 600)
  fs[t] = v;
  __syncthreads();
  #pragma unroll
  for (int off = 128; off > 0; off >>= 1) {
    if (t < off) fs[t] += fs[t + off];
    __syncthreads();
  }
  const float S = fs[0];

  int k3[3] = {0, 0, 0};
  int c = 0;
  const int n0 = t * 3;
  if (t < 200) {
    #pragma unroll
    for (int k = 0; k < 3; ++k) {
      const float a = sAP[n0 + k] / (S + kEps);
      k3[k] = (a > kThr) ? 1 : 0;   // mask==0 => ap==0 => a==0 => not kept
      c += k3[k];
    }
  }
  // 256-thread exclusive scan (wave scan + wave totals)
  int incl = c;
  #pragma unroll
  for (int off = 1; off < 64; off <<= 1) {
    const int u = __shfl_up(incl, off, 64);
    if (lane >= off) incl += u;
  }
  if (lane == 63) wtot[wave] = incl;
  __syncthreads();
  int offtot = 0, K = 0;
  #pragma unroll
  for (int w2 = 0; w2 < 4; ++w2) {
    const int u = wtot[w2];
    if (w2 < wave) offtot += u;
    K += u;
  }
  int run = incl - c + offtot;       // kept nodes before n0
  if (t < 200) {
    #pragma unroll
    for (int k = 0; k < 3; ++k) {
      const int n = n0 + k;
      if (k3[k]) { sidx[run] = n; ++run; }
      else       { sidx[K + (n - run)] = n; }
    }
  }
  __syncthreads();

  if (i0 == 0) {
    for (int n = t; n < N_NODES; n += 256)
      mo[b * N_NODES + n] = (n < K) ? 1.0f : 0.0f;
  }

  const float Sd = S + kEps;
  const int kq = K >> 2;             // float4s fully inside [0,K)
  const float* xb  = x  + (size_t)b * N_NODES * C_DIM;
  float*       xob = xo + (size_t)b * N_NODES * C_DIM;
  const float* Ab  = A  + (size_t)b * N_NODES * N_NODES;
  float*       Aob = Ao + (size_t)b * N_NODES * N_NODES;

  for (int ii = wave; ii < ROWTILE; ii += 4) {
    const int i = i0 + ii;
    if (i >= N_NODES) break;
    const int src = sidx[i];

    // ---- x row: xo[b,i,:] = x[b,src,:] * alpha[src] ----
    const float a = sAP[src] / Sd;
    float4 xv = reinterpret_cast<const float4*>(xb + (size_t)src * C_DIM)[lane];
    xv.x *= a; xv.y *= a; xv.z *= a; xv.w *= a;
    reinterpret_cast<float4*>(xob + (size_t)i * C_DIM)[lane] = xv;

    // ---- A row ----
    float4* orow = reinterpret_cast<float4*>(Aob + (size_t)i * N_NODES);
    if (i < K) {
      const float* Arow = Ab + (size_t)src * N_NODES;
      for (int j4 = lane; j4 < NV4; j4 += 64) {
        float4 w4 = {0.f, 0.f, 0.f, 0.f};
        if (j4 < kq) {
          const int j = j4 * 4;
          w4.x = Arow[sidx[j + 0]];
          w4.y = Arow[sidx[j + 1]];
          w4.z = Arow[sidx[j + 2]];
          w4.w = Arow[sidx[j + 3]];
        } else if (j4 == kq) {
          const int j = j4 * 4;
          if (j + 0 < K) w4.x = Arow[sidx[j + 0]];
          if (j + 1 < K) w4.y = Arow[sidx[j + 1]];
          if (j + 2 < K) w4.z = Arow[sidx[j + 2]];
        }
        orow[j4] = w4;
      }
    } else {
      const float4 z = {0.f, 0.f, 0.f, 0.f};
      for (int j4 = lane; j4 < NV4; j4 += 64) orow[j4] = z;
    }
  }
}

// ---------------------------------------------------------------------------
extern "C" void kernel_launch(void* const* d_in, const int* in_sizes, int n_in,
                              void* d_out, int out_size, void* d_ws, size_t ws_size,
                              hipStream_t stream) {
  const float* x    = (const float*)d_in[0];
  const float* A    = (const float*)d_in[1];
  const int*   mask = (const int*)d_in[2];
  const float* W    = (const float*)d_in[3];

  const size_t BN = (size_t)B_DIM * N_NODES;

  float* xo = (float*)d_out;                       // (B,N,C)
  float* Ao = xo + BN * C_DIM;                     // (B,N,N)
  float* mo = Ao + BN * N_NODES;                   // (B,N) as 0.0/1.0

  float* alpha_pre = (float*)d_ws;                 // B*N floats

  k_scores<<<SBLOCKS, 256, 0, stream>>>(x, W, mask, alpha_pre);
  k_gather<<<GBLOCKS, 256, 0, stream>>>(x, A, alpha_pre, xo, Ao, mo);
}